// Round 4
// baseline (1643.273 us; speedup 1.0000x reference)
//
#include <hip/hip_runtime.h>
#include <math.h>

#define NLOC 100

typedef __attribute__((ext_vector_type(8))) _Float16 half8;
typedef __attribute__((ext_vector_type(4))) float f32x4;

// ---------------- workspace layout (float offsets) ----------------
#define H_OFF     0            // 51200 f32
#define QKV_OFF   51200        // 204800 f32 [100][2048]
#define FFN_OFF   256000       // 102400 f32 slots = 100*2048 f16
#define ACTA_OFF  358400       // 320064 f32 slots
#define ACTB_OFF  678464       // 320064
#define CWH_OFF   998528       // 555776 f32 slots = 1111552 f16 conv wts L2..L10
#define CW1_OFF   1554304      // 320 f32: conv1 weights float4[8*9]
#define WQKVT_OFF 1554624      // 6291456 f32 slots (12*2048*512 f16)
#define W1T_OFF   7846080      // 6291456
#define W2T_OFF   14137536     // 6291456
// end 20428992 floats = 81.7 MB

struct WPack { const float* w[9]; };   // conv layers 2..10
struct WTArgs { const float* src[5]; };

// ---------------- conv1 weight repack: [8][3][3][3] -> float4[oc*9+kk] ----------------
__global__ __launch_bounds__(256) void cw1repack(const float* __restrict__ w, float* __restrict__ w4)
{
    int idx = blockIdx.x*256 + threadIdx.x;   // 288 = 8*9*4
    if (idx >= 288) return;
    int c = idx & 3;
    int r = idx >> 2;
    int oc = r / 9, kk = r - oc*9;
    int ky = kk/3, kx = kk - ky*3;
    float v = 0.f;
    if (c < 3) v = w[((oc*3 + c)*3 + ky)*3 + kx];
    w4[idx] = v;
}

// ---------------- conv weights L2..L10 -> f16 Bt[oc][Kpad], k = kk*Cin + ic ----------------
__global__ __launch_bounds__(256) void cwrepack(WPack wp, unsigned short* __restrict__ dst)
{
    const int Cin[9]  = {8,16,32,32,64,64,128,128,256};
    const int shift[9]= {3,4,5,5,6,6,7,7,8};
    const int KS[9]   = {3,3,3,3,3,3,3,3,2};
    const int Kpad[9] = {96,160,288,288,576,576,1152,1152,1024};
    const int off[10] = {0,1536,6656,15872,34304,71168,144896,292352,587264,1111552};
    const int total = 1111552;
    for (int i = blockIdx.x*blockDim.x + threadIdx.x; i < total; i += gridDim.x*blockDim.x) {
        int l = 0;
        while (i >= off[l+1]) ++l;
        int rem = i - off[l];
        int kp = Kpad[l];
        int oc = rem / kp;
        int k  = rem - oc*kp;
        int ci = Cin[l];
        int ic = k & (ci - 1);
        int kk = k >> shift[l];
        int ks = KS[l], k2 = ks*ks;
        float v = 0.f;
        if (kk < k2) {
            int ky = kk / ks, kx = kk - ky*ks;
            v = wp.w[l][((oc*ci + ic)*ks + ky)*ks + kx];
        }
        _Float16 hv = (_Float16)v;
        dst[i] = __builtin_bit_cast(unsigned short, hv);
    }
}

// ---------------- merged transformer weight transpose fp32->f16 ----------------
// segments: 0=Wq 1=Wk 2=Wv (into wqkvt) 3=W1 4=W2
__global__ __launch_bounds__(256) void wtrans_all(WTArgs wa,
    unsigned short* __restrict__ wqkvt, unsigned short* __restrict__ w1t,
    unsigned short* __restrict__ w2t)
{
    const int pre[6]  = {0, 3072, 6144, 12288, 24576, 36864};
    const int tX[5]   = {4, 4, 8, 64, 16};
    const int tY[5]   = {16, 16, 16, 16, 64};
    const int Kd[5]   = {512, 512, 512, 512, 2048};
    const int Nd[5]   = {128, 128, 256, 2048, 512};
    const int mpl[5]  = {4, 4, 4, 1, 1};
    const int dls[5]  = {1048576, 1048576, 1048576, 1048576, 1048576};
    const int dbase[5]= {0, 262144, 524288, 0, 0};
    __shared__ float tsh[32][33];
    int b = blockIdx.x;
    int seg = 0;
    while (b >= pre[seg+1]) ++seg;
    int lb = b - pre[seg];
    int tpm = tX[seg]*tY[seg];
    int mz = lb / tpm;
    int r = lb - mz*tpm;
    int ty_ = r / tX[seg];
    int tx_ = r - ty_*tX[seg];
    int K = Kd[seg], N = Nd[seg];
    int layer = mz / mpl[seg];
    int mi = mz - layer*mpl[seg];
    const float* s = wa.src[seg] + (size_t)mz * K * N;
    unsigned short* base = (seg < 3) ? wqkvt : (seg == 3 ? w1t : w2t);
    unsigned short* d = base + (size_t)layer*dls[seg] + dbase[seg] + (size_t)mi * N * K;
    int n0 = tx_*32, k0 = ty_*32;
    int lx = threadIdx.x & 31, ly = threadIdx.x >> 5;
    #pragma unroll
    for (int i = 0; i < 32; i += 8) tsh[ly + i][lx] = s[(size_t)(k0 + ly + i)*N + n0 + lx];
    __syncthreads();
    #pragma unroll
    for (int i = 0; i < 32; i += 8) {
        _Float16 hv = (_Float16)tsh[lx][ly + i];
        d[(size_t)(n0 + ly + i)*K + k0 + lx] = __builtin_bit_cast(unsigned short, hv);
    }
}

// ---------------- conv1: thread per pixel, 8 ocs, reads x directly ----------------
__global__ __launch_bounds__(256) void conv1k(const float* __restrict__ x,
    const float4* __restrict__ w4, const float* __restrict__ bias, unsigned short* __restrict__ out)
{
    int idx = blockIdx.x*256 + threadIdx.x;   // 32400 = 100*324
    if (idx >= 32400) return;
    int p = idx / 324;
    int s = idx - p*324;
    int sy = s / 18, sx = s - sy*18;
    int pi = p/10, pj = p - pi*10;
    const float* xb = x + (pj*20 + sy)*200 + pi*20 + sx;
    float acc[8];
    #pragma unroll
    for (int o = 0; o < 8; ++o) acc[o] = bias[o];
    #pragma unroll
    for (int ky = 0; ky < 3; ++ky)
        #pragma unroll
        for (int kx = 0; kx < 3; ++kx) {
            float r = xb[ky*200 + kx];
            float g = xb[40000 + ky*200 + kx];
            float bch = xb[80000 + ky*200 + kx];
            #pragma unroll
            for (int o = 0; o < 8; ++o) {
                float4 wv = w4[o*9 + ky*3 + kx];
                acc[o] += r*wv.x + g*wv.y + bch*wv.z;
            }
        }
    unsigned short h8[8];
    #pragma unroll
    for (int o = 0; o < 8; ++o) {
        _Float16 hv = (_Float16)acc[o];   // no relu after conv1
        h8[o] = __builtin_bit_cast(unsigned short, hv);
    }
    *(uint4*)(out + (size_t)idx*8) = *(const uint4*)h8;
}

// ---------------- MFMA conv: wave per 16x16 tile, implicit im2col ----------------
template<int CIN, int COUT, int KS, int HIN, int WIN, int HOUT, int WOUT, int KPAD, int RELU, int LAST>
__global__ __launch_bounds__(256) void convM(const unsigned short* __restrict__ in,
    const unsigned short* __restrict__ wth, const float* __restrict__ bias,
    unsigned short* __restrict__ out, float* __restrict__ hout)
{
    constexpr int HW = HOUT*WOUT;
    constexpr int M = 100*HW;
    constexpr int MT = (M + 15)/16;
    constexpr int NT = COUT/16;
    int wave = threadIdx.x >> 6, lane = threadIdx.x & 63;
    int t = blockIdx.x*4 + wave;
    if (t >= MT*NT) return;
    int mt = t % MT, nt = t / MT;
    int mrow = lane & 15, quad = lane >> 4;
    int mg = mt*16 + mrow; if (mg >= M) mg = M - 1;
    int p = mg / HW, s = mg - p*HW;
    int sy = s / WOUT, sx = s - sy*WOUT;
    const unsigned short* ap = in + ((size_t)((p*HIN + sy)*WIN + sx))*CIN;
    const unsigned short* bp = wth + ((size_t)(nt*16 + mrow))*KPAD + quad*8;
    f32x4 acc = {0.f, 0.f, 0.f, 0.f};
    #pragma unroll
    for (int k0 = 0; k0 < KPAD; k0 += 32) {
        int k = k0 + quad*8;
        int kk = k / CIN; if (kk > KS*KS - 1) kk = KS*KS - 1;
        int ky = kk / KS, kx = kk - ky*KS;
        uint4 av = *(const uint4*)(ap + (ky*WIN + kx)*CIN + (k & (CIN-1)));
        uint4 bv = *(const uint4*)(bp + k0);
        acc = __builtin_amdgcn_mfma_f32_16x16x32_f16(
            __builtin_bit_cast(half8, av), __builtin_bit_cast(half8, bv), acc, 0, 0, 0);
    }
    int n = nt*16 + mrow;
    float bv = bias[n];
    #pragma unroll
    for (int r = 0; r < 4; ++r) {
        int m = mt*16 + quad*4 + r;
        if (m < M) {
            float v = acc[r] + bv;
            if (RELU) v = fmaxf(v, 0.f);
            if (LAST) {
                int pi = m / 10;
                float pos = 20.f * (float)pi;
                int dd = n & 255;
                float inv = powf(10000.f, (float)dd * (1.f/128.f));
                float ang = pos / inv;
                v += (n < 256) ? sinf(ang) : cosf(ang);
                hout[(size_t)m*512 + n] = v;
            } else {
                _Float16 hv = (_Float16)v;
                out[(size_t)m*COUT + n] = __builtin_bit_cast(unsigned short, hv);
            }
        }
    }
}

// ---------------- MFMA GEMM (transformer), compile-time K chunk ----------------
template<int KCHUNK, int ABITS, int RELU, int ATOMIC, int STOREH>
__global__ __launch_bounds__(256) void gemm16(
    const void* __restrict__ Av, int lda,
    const unsigned short* __restrict__ Bt, int K,
    const float* __restrict__ bias,
    float* __restrict__ C, unsigned short* __restrict__ Ch, int ldc)
{
    int lane = threadIdx.x & 63;
    int wave = threadIdx.x >> 6;
    int mrow = lane & 15, quad = lane >> 4;
    int n0 = blockIdx.x*64 + wave*16;
    int m0 = blockIdx.y*16;
    int arow = m0 + mrow; if (arow > 99) arow = 99;
    int k0 = blockIdx.z * KCHUNK;
    const unsigned short* bp = Bt + (size_t)(n0 + mrow)*K + quad*8 + k0;
    f32x4 acc = {0.f, 0.f, 0.f, 0.f};
    if (ABITS == 16) {
        const unsigned short* ap = (const unsigned short*)Av + (size_t)arow*lda + quad*8 + k0;
        #pragma unroll 8
        for (int k = 0; k < KCHUNK; k += 32) {
            uint4 au = *(const uint4*)(ap + k);
            uint4 bu = *(const uint4*)(bp + k);
            acc = __builtin_amdgcn_mfma_f32_16x16x32_f16(
                __builtin_bit_cast(half8, au), __builtin_bit_cast(half8, bu), acc, 0, 0, 0);
        }
    } else {
        const float* ap = (const float*)Av + (size_t)arow*lda + quad*8 + k0;
        #pragma unroll 8
        for (int k = 0; k < KCHUNK; k += 32) {
            float4 f0 = *(const float4*)(ap + k);
            float4 f1 = *(const float4*)(ap + k + 4);
            half8 af;
            af[0] = (_Float16)f0.x; af[1] = (_Float16)f0.y;
            af[2] = (_Float16)f0.z; af[3] = (_Float16)f0.w;
            af[4] = (_Float16)f1.x; af[5] = (_Float16)f1.y;
            af[6] = (_Float16)f1.z; af[7] = (_Float16)f1.w;
            uint4 bu = *(const uint4*)(bp + k);
            acc = __builtin_amdgcn_mfma_f32_16x16x32_f16(
                af, __builtin_bit_cast(half8, bu), acc, 0, 0, 0);
        }
    }
    int n = n0 + mrow;
    float bv = (bias != nullptr && blockIdx.z == 0) ? bias[n] : 0.f;
    #pragma unroll
    for (int r = 0; r < 4; ++r) {
        int row = m0 + quad*4 + r;
        if (row < 100) {
            float v = acc[r] + bv;
            if (RELU) v = fmaxf(v, 0.f);
            if (ATOMIC) atomicAdd(&C[(size_t)row*ldc + n], v);
            else if (C != nullptr) C[(size_t)row*ldc + n] = v;
            if (STOREH) {
                _Float16 hv = (_Float16)v;
                Ch[(size_t)row*ldc + n] = __builtin_bit_cast(unsigned short, hv);
            }
        }
    }
}

// ---------------- fused attention + O-proj + residual: block per query row ----------------
__global__ __launch_bounds__(512) void attn_fused(
    const float* __restrict__ qkv, const float* __restrict__ Wo,
    float* __restrict__ h)
{
    __shared__ float qs[512];
    __shared__ float sc[4][128];
    __shared__ float os[1024];
    __shared__ float sred[4];
    int n = blockIdx.x;
    int t = threadIdx.x;
    qs[t] = qkv[(size_t)n*2048 + t];
    __syncthreads();
    if (t < 400) {
        int hh = t / 100, m = t - hh*100;
        const float4* q4 = (const float4*)(qs + hh*128);
        const float4* kp = (const float4*)(qkv + (size_t)m*2048 + 512 + hh*128);
        float s0=0.f, s1=0.f, s2=0.f, s3=0.f;
        #pragma unroll 8
        for (int j = 0; j < 32; ++j) {
            float4 a = q4[j], b = kp[j];
            s0 += a.x*b.x; s1 += a.y*b.y; s2 += a.z*b.z; s3 += a.w*b.w;
        }
        sc[hh][m] = (s0+s1+s2+s3) * 0.1f;   // scale = 1/sqrt(N_LOC) quirk
    }
    __syncthreads();
    int wv = t >> 6, ln = t & 63;
    if (wv < 4) {
        float v0 = (ln < 100)    ? sc[wv][ln]    : -1e30f;
        float v1 = (ln+64 < 100) ? sc[wv][ln+64] : -1e30f;
        float m = fmaxf(v0, v1);
        for (int o = 32; o > 0; o >>= 1) m = fmaxf(m, __shfl_down(m, o));
        m = __shfl(m, 0);
        float e0 = expf(v0 - m);
        float e1 = expf(v1 - m);
        if (ln < 100)    sc[wv][ln]    = e0;
        if (ln+64 < 100) sc[wv][ln+64] = e1;
        float sm = ((ln < 100) ? e0 : 0.f) + ((ln+64 < 100) ? e1 : 0.f);
        for (int o = 32; o > 0; o >>= 1) sm += __shfl_down(sm, o);
        if (ln == 0) sred[wv] = 1.0f / sm;
    }
    __syncthreads();
    // AV: thread t -> (head t>>8 and t>>8 + 2, dv = t & 255)
    {
        int dv = t & 255;
        int h0 = t >> 8;
        float o0 = 0.f, o1 = 0.f;
        const float* vb = qkv + 1024;
        #pragma unroll 4
        for (int m = 0; m < 100; ++m) {
            const float* vr = vb + (size_t)m*2048 + dv;
            o0 += sc[h0][m]   * vr[h0*256];
            o1 += sc[h0+2][m] * vr[(h0+2)*256];
        }
        os[h0*256 + dv]     = o0 * sred[h0];
        os[(h0+2)*256 + dv] = o1 * sred[h0+2];
    }
    __syncthreads();
    // O-proj + residual: c = t
    float acc = h[(size_t)n*512 + t];
    const float* wp = Wo + t;
    #pragma unroll 8
    for (int k = 0; k < 1024; ++k) acc += os[k] * wp[(size_t)k*512];
    h[(size_t)n*512 + t] = acc;
}

// ---------------- final copy ----------------
__global__ __launch_bounds__(256) void copyk(const float* __restrict__ s, float* __restrict__ d, int n)
{
    int i = blockIdx.x*256 + threadIdx.x;
    if (i < n) d[i] = s[i];
}

// ---------------- launch ----------------
extern "C" void kernel_launch(void* const* d_in, const int* in_sizes, int n_in,
                              void* d_out, int out_size, void* d_ws, size_t ws_size,
                              hipStream_t stream)
{
    const float* x = (const float*)d_in[0];
    const float* cw1 = (const float*)d_in[1];
    const float* cb[10];
    WPack wpk;
    for (int i = 0; i < 10; ++i) cb[i] = (const float*)d_in[2 + 2*i];
    for (int i = 0; i < 9; ++i)  wpk.w[i] = (const float*)d_in[3 + 2*i];  // conv layers 2..10
    const float* Wq = (const float*)d_in[21];
    const float* Wk = (const float*)d_in[22];
    const float* Wv = (const float*)d_in[23];
    const float* Wo = (const float*)d_in[24];
    const float* W1 = (const float*)d_in[25];
    const float* b1 = (const float*)d_in[26];
    const float* W2 = (const float*)d_in[27];
    const float* b2 = (const float*)d_in[28];

    float* ws = (float*)d_ws;
    float* h   = ws + H_OFF;
    float* qkv = ws + QKV_OFF;
    unsigned short* ffn  = (unsigned short*)(ws + FFN_OFF);
    unsigned short* aA   = (unsigned short*)(ws + ACTA_OFF);
    unsigned short* aB   = (unsigned short*)(ws + ACTB_OFF);
    unsigned short* cwh  = (unsigned short*)(ws + CWH_OFF);
    float* cw14 = ws + CW1_OFF;
    unsigned short* wqkvt = (unsigned short*)(ws + WQKVT_OFF);
    unsigned short* w1t   = (unsigned short*)(ws + W1T_OFF);
    unsigned short* w2t   = (unsigned short*)(ws + W2T_OFF);

    // weight prep
    cw1repack<<<2, 256, 0, stream>>>(cw1, cw14);
    cwrepack<<<2172, 256, 0, stream>>>(wpk, cwh);
    WTArgs wargs; wargs.src[0] = Wq; wargs.src[1] = Wk; wargs.src[2] = Wv;
    wargs.src[3] = W1; wargs.src[4] = W2;
    wtrans_all<<<36864, 256, 0, stream>>>(wargs, wqkvt, w1t, w2t);

    // conv stack
    conv1k<<<127, 256, 0, stream>>>(x, (const float4*)cw14, cb[0], aA);
    convM<8,  16, 3,18,18,16,16,  96,1,0><<<400, 256, 0, stream>>>(aA, cwh + 0,      cb[1], aB, nullptr);
    convM<16, 32, 3,16,16,14,14, 160,0,0><<<613, 256, 0, stream>>>(aB, cwh + 1536,   cb[2], aA, nullptr);
    convM<32, 32, 3,14,14,12,12, 288,1,0><<<450, 256, 0, stream>>>(aA, cwh + 6656,   cb[3], aB, nullptr);
    convM<32, 64, 3,12,12,10,10, 288,1,0><<<625, 256, 0, stream>>>(aB, cwh + 15872,  cb[4], aA, nullptr);
    convM<64, 64, 3,10,10, 8, 8, 576,1,0><<<400, 256, 0, stream>>>(aA, cwh + 34304,  cb[5], aB, nullptr);
    convM<64,128, 3, 8, 8, 6, 6, 576,1,0><<<450, 256, 0, stream>>>(aB, cwh + 71168,  cb[6], aA, nullptr);
    convM<128,128,3, 6, 6, 4, 4,1152,1,0><<<200, 256, 0, stream>>>(aA, cwh + 144896, cb[7], aB, nullptr);
    convM<128,256,3, 4, 4, 2, 2,1152,1,0><<<100, 256, 0, stream>>>(aB, cwh + 292352, cb[8], aA, nullptr);
    convM<256,512,2, 2, 2, 1, 1,1024,0,1><<<56,  256, 0, stream>>>(aA, cwh + 587264, cb[9], nullptr, h);

    // transformer
    for (int n = 0; n < 12; ++n) {
        const unsigned short* Bq  = wqkvt + (size_t)n * 2048 * 512;
        const unsigned short* Bf1 = w1t   + (size_t)n * 2048 * 512;
        const unsigned short* Bf2 = w2t   + (size_t)n * 512 * 2048;
        gemm16<512,32,0,0,0><<<dim3(32, 7, 1), 256, 0, stream>>>(h, 512, Bq, 512,
            nullptr, qkv, nullptr, 2048);
        attn_fused<<<100, 512, 0, stream>>>(qkv, Wo + (size_t)n*1024*512, h);
        gemm16<512,32,1,0,1><<<dim3(32, 7, 1), 256, 0, stream>>>(h, 512, Bf1, 512,
            b1 + (size_t)n*2048, nullptr, ffn, 2048);
        gemm16<512,16,0,1,0><<<dim3(8, 7, 4), 256, 0, stream>>>(ffn, 2048, Bf2, 2048,
            b2 + (size_t)n*512, h, nullptr, 512);
    }
    copyk<<<200, 256, 0, stream>>>(h, (float*)d_out, NLOC*512);
}

// Round 5
// 914.360 us; speedup vs baseline: 1.7972x; 1.7972x over previous
//
#include <hip/hip_runtime.h>
#include <math.h>

#define NLOC 100

typedef __attribute__((ext_vector_type(8))) _Float16 half8;
typedef __attribute__((ext_vector_type(4))) float f32x4;

// ---------------- workspace layout (float offsets) ----------------
#define H_OFF     0            // 51200 f32
#define QKV_OFF   51200        // 204800 f32 [100][2048]
#define OCAT_OFF  256000       // 51200 f32 slots = 100*1024 f16
#define FFN_OFF   307200       // 102400 f32 slots = 100*2048 f16
#define ACTA_OFF  409600       // 320064 f32 slots
#define ACTB_OFF  729664       // 320064
#define CWH_OFF   1049728      // 555776 f32 slots = 1111552 f16 conv wts L2..L10
#define CW1_OFF   1605504      // 320 f32: conv1 weights float4[8*9]
#define WQKVT_OFF 1605824      // 6291456 f32 slots (12*2048*512 f16)
#define WOT_OFF   7897280      // 3145728 f32 slots (12*512*1024 f16)
#define W1T_OFF   11043008     // 6291456
#define W2T_OFF   17334464     // 6291456
// end 23625920 floats = 94.5 MB

struct WPack { const float* w[9]; };   // conv layers 2..10
struct WTArgs { const float* src[6]; };

// ---------------- conv1 weight repack: [8][3][3][3] -> float4[oc*9+kk] ----------------
__global__ __launch_bounds__(256) void cw1repack(const float* __restrict__ w, float* __restrict__ w4)
{
    int idx = blockIdx.x*256 + threadIdx.x;   // 288 = 8*9*4
    if (idx >= 288) return;
    int c = idx & 3;
    int r = idx >> 2;
    int oc = r / 9, kk = r - oc*9;
    int ky = kk/3, kx = kk - ky*3;
    float v = 0.f;
    if (c < 3) v = w[((oc*3 + c)*3 + ky)*3 + kx];
    w4[idx] = v;
}

// ---------------- conv weights L2..L10 -> f16 Bt[oc][Kpad], k = kk*Cin + ic ----------------
__global__ __launch_bounds__(256) void cwrepack(WPack wp, unsigned short* __restrict__ dst)
{
    const int Cin[9]  = {8,16,32,32,64,64,128,128,256};
    const int shift[9]= {3,4,5,5,6,6,7,7,8};
    const int KS[9]   = {3,3,3,3,3,3,3,3,2};
    const int Kpad[9] = {96,160,288,288,576,576,1152,1152,1024};
    const int off[10] = {0,1536,6656,15872,34304,71168,144896,292352,587264,1111552};
    const int total = 1111552;
    for (int i = blockIdx.x*blockDim.x + threadIdx.x; i < total; i += gridDim.x*blockDim.x) {
        int l = 0;
        while (i >= off[l+1]) ++l;
        int rem = i - off[l];
        int kp = Kpad[l];
        int oc = rem / kp;
        int k  = rem - oc*kp;
        int ci = Cin[l];
        int ic = k & (ci - 1);
        int kk = k >> shift[l];
        int ks = KS[l], k2 = ks*ks;
        float v = 0.f;
        if (kk < k2) {
            int ky = kk / ks, kx = kk - ky*ks;
            v = wp.w[l][((oc*ci + ic)*ks + ky)*ks + kx];
        }
        _Float16 hv = (_Float16)v;
        dst[i] = __builtin_bit_cast(unsigned short, hv);
    }
}

// ---------------- merged transformer weight transpose fp32->f16 ----------------
// segments: 0=Wq 1=Wk 2=Wv (into wqkvt) 3=W1 4=W2 5=Wo
__global__ __launch_bounds__(256) void wtrans_all(WTArgs wa,
    unsigned short* __restrict__ wqkvt, unsigned short* __restrict__ w1t,
    unsigned short* __restrict__ w2t, unsigned short* __restrict__ wot)
{
    const int pre[7]  = {0, 3072, 6144, 12288, 24576, 36864, 43008};
    const int tX[6]   = {4, 4, 8, 64, 16, 16};
    const int Kd[6]   = {512, 512, 512, 512, 2048, 1024};
    const int Nd[6]   = {128, 128, 256, 2048, 512, 512};
    const int mpl[6]  = {4, 4, 4, 1, 1, 1};
    const int dls[6]  = {1048576, 1048576, 1048576, 1048576, 1048576, 524288};
    const int dbase[6]= {0, 262144, 524288, 0, 0, 0};
    __shared__ float tsh[32][33];
    int b = blockIdx.x;
    int seg = 0;
    while (b >= pre[seg+1]) ++seg;
    int lb = b - pre[seg];
    int K = Kd[seg], N = Nd[seg];
    int tpm = (N/32)*(K/32);
    int mz = lb / tpm;
    int r = lb - mz*tpm;
    int ty_ = r / tX[seg];
    int tx_ = r - ty_*tX[seg];
    int layer = mz / mpl[seg];
    int mi = mz - layer*mpl[seg];
    const float* s = wa.src[seg] + (size_t)mz * K * N;
    unsigned short* base = (seg < 3) ? wqkvt : (seg == 3 ? w1t : (seg == 4 ? w2t : wot));
    unsigned short* d = base + (size_t)layer*dls[seg] + dbase[seg] + (size_t)mi * N * K;
    int n0 = tx_*32, k0 = ty_*32;
    int lx = threadIdx.x & 31, ly = threadIdx.x >> 5;
    #pragma unroll
    for (int i = 0; i < 32; i += 8) tsh[ly + i][lx] = s[(size_t)(k0 + ly + i)*N + n0 + lx];
    __syncthreads();
    #pragma unroll
    for (int i = 0; i < 32; i += 8) {
        _Float16 hv = (_Float16)tsh[lx][ly + i];
        d[(size_t)(n0 + ly + i)*K + k0 + lx] = __builtin_bit_cast(unsigned short, hv);
    }
}

// ---------------- conv1: thread per pixel, 8 ocs, reads x directly ----------------
__global__ __launch_bounds__(256) void conv1k(const float* __restrict__ x,
    const float4* __restrict__ w4, const float* __restrict__ bias, unsigned short* __restrict__ out)
{
    int idx = blockIdx.x*256 + threadIdx.x;   // 32400 = 100*324
    if (idx >= 32400) return;
    int p = idx / 324;
    int s = idx - p*324;
    int sy = s / 18, sx = s - sy*18;
    int pi = p/10, pj = p - pi*10;
    const float* xb = x + (pj*20 + sy)*200 + pi*20 + sx;
    float acc[8];
    #pragma unroll
    for (int o = 0; o < 8; ++o) acc[o] = bias[o];
    #pragma unroll
    for (int ky = 0; ky < 3; ++ky)
        #pragma unroll
        for (int kx = 0; kx < 3; ++kx) {
            float r = xb[ky*200 + kx];
            float g = xb[40000 + ky*200 + kx];
            float bch = xb[80000 + ky*200 + kx];
            #pragma unroll
            for (int o = 0; o < 8; ++o) {
                float4 wv = w4[o*9 + ky*3 + kx];
                acc[o] += r*wv.x + g*wv.y + bch*wv.z;
            }
        }
    unsigned short h8[8];
    #pragma unroll
    for (int o = 0; o < 8; ++o) {
        _Float16 hv = (_Float16)acc[o];   // no relu after conv1
        h8[o] = __builtin_bit_cast(unsigned short, hv);
    }
    *(uint4*)(out + (size_t)idx*8) = *(const uint4*)h8;
}

// ---------------- MFMA conv: wave per 16x16 tile, implicit im2col ----------------
template<int CIN, int COUT, int KS, int HIN, int WIN, int HOUT, int WOUT, int KPAD, int RELU, int LAST>
__global__ __launch_bounds__(256) void convM(const unsigned short* __restrict__ in,
    const unsigned short* __restrict__ wth, const float* __restrict__ bias,
    unsigned short* __restrict__ out, float* __restrict__ hout)
{
    constexpr int HW = HOUT*WOUT;
    constexpr int M = 100*HW;
    constexpr int MT = (M + 15)/16;
    constexpr int NT = COUT/16;
    int wave = threadIdx.x >> 6, lane = threadIdx.x & 63;
    int t = blockIdx.x*4 + wave;
    if (t >= MT*NT) return;
    int mt = t % MT, nt = t / MT;
    int mrow = lane & 15, quad = lane >> 4;
    int mg = mt*16 + mrow; if (mg >= M) mg = M - 1;
    int p = mg / HW, s = mg - p*HW;
    int sy = s / WOUT, sx = s - sy*WOUT;
    const unsigned short* ap = in + ((size_t)((p*HIN + sy)*WIN + sx))*CIN;
    const unsigned short* bp = wth + ((size_t)(nt*16 + mrow))*KPAD + quad*8;
    f32x4 acc = {0.f, 0.f, 0.f, 0.f};
    #pragma unroll
    for (int k0 = 0; k0 < KPAD; k0 += 32) {
        int k = k0 + quad*8;
        int kk = k / CIN; if (kk > KS*KS - 1) kk = KS*KS - 1;
        int ky = kk / KS, kx = kk - ky*KS;
        uint4 av = *(const uint4*)(ap + (ky*WIN + kx)*CIN + (k & (CIN-1)));
        uint4 bv = *(const uint4*)(bp + k0);
        acc = __builtin_amdgcn_mfma_f32_16x16x32_f16(
            __builtin_bit_cast(half8, av), __builtin_bit_cast(half8, bv), acc, 0, 0, 0);
    }
    int n = nt*16 + mrow;
    float bv = bias[n];
    #pragma unroll
    for (int r = 0; r < 4; ++r) {
        int m = mt*16 + quad*4 + r;
        if (m < M) {
            float v = acc[r] + bv;
            if (RELU) v = fmaxf(v, 0.f);
            if (LAST) {
                int pi = m / 10;
                float pos = 20.f * (float)pi;
                int dd = n & 255;
                float inv = powf(10000.f, (float)dd * (1.f/128.f));
                float ang = pos / inv;
                v += (n < 256) ? sinf(ang) : cosf(ang);
                hout[(size_t)m*512 + n] = v;
            } else {
                _Float16 hv = (_Float16)v;
                out[(size_t)m*COUT + n] = __builtin_bit_cast(unsigned short, hv);
            }
        }
    }
}

// ---------------- MFMA GEMM (transformer), compile-time K chunk ----------------
template<int KCHUNK, int ABITS, int RELU, int ATOMIC, int STOREH>
__global__ __launch_bounds__(256) void gemm16(
    const void* __restrict__ Av, int lda,
    const unsigned short* __restrict__ Bt, int K,
    const float* __restrict__ bias,
    float* __restrict__ C, unsigned short* __restrict__ Ch, int ldc)
{
    int lane = threadIdx.x & 63;
    int wave = threadIdx.x >> 6;
    int mrow = lane & 15, quad = lane >> 4;
    int n0 = blockIdx.x*64 + wave*16;
    int m0 = blockIdx.y*16;
    int arow = m0 + mrow; if (arow > 99) arow = 99;
    int k0 = blockIdx.z * KCHUNK;
    const unsigned short* bp = Bt + (size_t)(n0 + mrow)*K + quad*8 + k0;
    f32x4 acc = {0.f, 0.f, 0.f, 0.f};
    if (ABITS == 16) {
        const unsigned short* ap = (const unsigned short*)Av + (size_t)arow*lda + quad*8 + k0;
        #pragma unroll 8
        for (int k = 0; k < KCHUNK; k += 32) {
            uint4 au = *(const uint4*)(ap + k);
            uint4 bu = *(const uint4*)(bp + k);
            acc = __builtin_amdgcn_mfma_f32_16x16x32_f16(
                __builtin_bit_cast(half8, au), __builtin_bit_cast(half8, bu), acc, 0, 0, 0);
        }
    } else {
        const float* ap = (const float*)Av + (size_t)arow*lda + quad*8 + k0;
        #pragma unroll 8
        for (int k = 0; k < KCHUNK; k += 32) {
            float4 f0 = *(const float4*)(ap + k);
            float4 f1 = *(const float4*)(ap + k + 4);
            half8 af;
            af[0] = (_Float16)f0.x; af[1] = (_Float16)f0.y;
            af[2] = (_Float16)f0.z; af[3] = (_Float16)f0.w;
            af[4] = (_Float16)f1.x; af[5] = (_Float16)f1.y;
            af[6] = (_Float16)f1.z; af[7] = (_Float16)f1.w;
            uint4 bu = *(const uint4*)(bp + k);
            acc = __builtin_amdgcn_mfma_f32_16x16x32_f16(
                af, __builtin_bit_cast(half8, bu), acc, 0, 0, 0);
        }
    }
    int n = n0 + mrow;
    float bv = (bias != nullptr && blockIdx.z == 0) ? bias[n] : 0.f;
    #pragma unroll
    for (int r = 0; r < 4; ++r) {
        int row = m0 + quad*4 + r;
        if (row < 100) {
            float v = acc[r] + bv;
            if (RELU) v = fmaxf(v, 0.f);
            if (ATOMIC) atomicAdd(&C[(size_t)row*ldc + n], v);
            else if (C != nullptr) C[(size_t)row*ldc + n] = v;
            if (STOREH) {
                _Float16 hv = (_Float16)v;
                Ch[(size_t)row*ldc + n] = __builtin_bit_cast(unsigned short, hv);
            }
        }
    }
}

// ---------------- attention: block per (head, query row) ----------------
__global__ __launch_bounds__(256) void attn_kernel(
    const float* __restrict__ qkv, unsigned short* __restrict__ ocat)
{
    __shared__ float qr[128];
    __shared__ float p[100];
    __shared__ float red[2];
    int bx = blockIdx.x;
    int hh = bx / 100, nn = bx - hh*100;
    int t = threadIdx.x;
    if (t < 128) qr[t] = qkv[(size_t)nn*2048 + hh*128 + t];
    __syncthreads();
    float sv = 0.f;
    if (t < 100) {
        const float4* kp = (const float4*)(qkv + (size_t)t*2048 + 512 + hh*128);
        const float4* q4 = (const float4*)qr;
        float s0=0.f, s1=0.f, s2=0.f, s3=0.f;
        #pragma unroll 8
        for (int j = 0; j < 32; ++j) {
            float4 a = q4[j], b = kp[j];
            s0 += a.x*b.x; s1 += a.y*b.y; s2 += a.z*b.z; s3 += a.w*b.w;
        }
        sv = (s0+s1+s2+s3) * 0.1f;    // scale = 1/sqrt(N_LOC) quirk
        p[t] = sv;
    }
    __syncthreads();
    if (t < 64) {
        float m = fmaxf(p[t], (t+64 < 100) ? p[t+64] : -1e30f);
        for (int o = 32; o > 0; o >>= 1) m = fmaxf(m, __shfl_down(m, o));
        if (t == 0) red[0] = m;
    }
    __syncthreads();
    float mx = red[0];
    if (t < 100) p[t] = expf(sv - mx);
    __syncthreads();
    if (t < 64) {
        float s = p[t] + ((t+64 < 100) ? p[t+64] : 0.f);
        for (int o = 32; o > 0; o >>= 1) s += __shfl_down(s, o);
        if (t == 0) red[1] = s;
    }
    __syncthreads();
    float inv = 1.0f / red[1];
    const float* vp = qkv + 1024 + hh*256 + t;
    float acc = 0.f;
    #pragma unroll 4
    for (int m = 0; m < 100; ++m) acc += p[m] * vp[(size_t)m*2048];
    _Float16 hv = (_Float16)(acc * inv);
    ocat[(size_t)nn*1024 + hh*256 + t] = __builtin_bit_cast(unsigned short, hv);
}

// ---------------- final copy ----------------
__global__ __launch_bounds__(256) void copyk(const float* __restrict__ s, float* __restrict__ d, int n)
{
    int i = blockIdx.x*256 + threadIdx.x;
    if (i < n) d[i] = s[i];
}

// ---------------- launch ----------------
extern "C" void kernel_launch(void* const* d_in, const int* in_sizes, int n_in,
                              void* d_out, int out_size, void* d_ws, size_t ws_size,
                              hipStream_t stream)
{
    const float* x = (const float*)d_in[0];
    const float* cw1 = (const float*)d_in[1];
    const float* cb[10];
    WPack wpk;
    for (int i = 0; i < 10; ++i) cb[i] = (const float*)d_in[2 + 2*i];
    for (int i = 0; i < 9; ++i)  wpk.w[i] = (const float*)d_in[3 + 2*i];  // conv layers 2..10
    const float* Wq = (const float*)d_in[21];
    const float* Wk = (const float*)d_in[22];
    const float* Wv = (const float*)d_in[23];
    const float* Wo = (const float*)d_in[24];
    const float* W1 = (const float*)d_in[25];
    const float* b1 = (const float*)d_in[26];
    const float* W2 = (const float*)d_in[27];
    const float* b2 = (const float*)d_in[28];

    float* ws = (float*)d_ws;
    float* h   = ws + H_OFF;
    float* qkv = ws + QKV_OFF;
    unsigned short* ocat = (unsigned short*)(ws + OCAT_OFF);
    unsigned short* ffn  = (unsigned short*)(ws + FFN_OFF);
    unsigned short* aA   = (unsigned short*)(ws + ACTA_OFF);
    unsigned short* aB   = (unsigned short*)(ws + ACTB_OFF);
    unsigned short* cwh  = (unsigned short*)(ws + CWH_OFF);
    float* cw14 = ws + CW1_OFF;
    unsigned short* wqkvt = (unsigned short*)(ws + WQKVT_OFF);
    unsigned short* wot   = (unsigned short*)(ws + WOT_OFF);
    unsigned short* w1t   = (unsigned short*)(ws + W1T_OFF);
    unsigned short* w2t   = (unsigned short*)(ws + W2T_OFF);

    // weight prep
    cw1repack<<<2, 256, 0, stream>>>(cw1, cw14);
    cwrepack<<<2172, 256, 0, stream>>>(wpk, cwh);
    WTArgs wargs;
    wargs.src[0] = Wq; wargs.src[1] = Wk; wargs.src[2] = Wv;
    wargs.src[3] = W1; wargs.src[4] = W2; wargs.src[5] = Wo;
    wtrans_all<<<43008, 256, 0, stream>>>(wargs, wqkvt, w1t, w2t, wot);

    // conv stack
    conv1k<<<127, 256, 0, stream>>>(x, (const float4*)cw14, cb[0], aA);
    convM<8,  16, 3,18,18,16,16,  96,1,0><<<400, 256, 0, stream>>>(aA, cwh + 0,      cb[1], aB, nullptr);
    convM<16, 32, 3,16,16,14,14, 160,0,0><<<613, 256, 0, stream>>>(aB, cwh + 1536,   cb[2], aA, nullptr);
    convM<32, 32, 3,14,14,12,12, 288,1,0><<<450, 256, 0, stream>>>(aA, cwh + 6656,   cb[3], aB, nullptr);
    convM<32, 64, 3,12,12,10,10, 288,1,0><<<625, 256, 0, stream>>>(aB, cwh + 15872,  cb[4], aA, nullptr);
    convM<64, 64, 3,10,10, 8, 8, 576,1,0><<<400, 256, 0, stream>>>(aA, cwh + 34304,  cb[5], aB, nullptr);
    convM<64,128, 3, 8, 8, 6, 6, 576,1,0><<<450, 256, 0, stream>>>(aB, cwh + 71168,  cb[6], aA, nullptr);
    convM<128,128,3, 6, 6, 4, 4,1152,1,0><<<200, 256, 0, stream>>>(aA, cwh + 144896, cb[7], aB, nullptr);
    convM<128,256,3, 4, 4, 2, 2,1152,1,0><<<100, 256, 0, stream>>>(aB, cwh + 292352, cb[8], aA, nullptr);
    convM<256,512,2, 2, 2, 1, 1,1024,0,1><<<56,  256, 0, stream>>>(aA, cwh + 587264, cb[9], nullptr, h);

    // transformer
    for (int n = 0; n < 12; ++n) {
        const unsigned short* Bq  = wqkvt + (size_t)n * 2048 * 512;
        const unsigned short* Bo  = wot   + (size_t)n * 512 * 1024;
        const unsigned short* Bf1 = w1t   + (size_t)n * 2048 * 512;
        const unsigned short* Bf2 = w2t   + (size_t)n * 512 * 2048;
        // qkv = h @ Wqkv  [100x2048]
        gemm16<512,32,0,0,0><<<dim3(32, 7, 1), 256, 0, stream>>>(h, 512, Bq, 512,
            nullptr, qkv, nullptr, 2048);
        attn_kernel<<<400, 256, 0, stream>>>(qkv, ocat);
        // h += ocat @ Wo  (K=1024 split 4)
        gemm16<256,16,0,1,0><<<dim3(8, 7, 4), 256, 0, stream>>>(ocat, 1024, Bo, 1024,
            nullptr, h, nullptr, 512);
        // ffn = relu(h @ W1 + b1) -> f16
        gemm16<512,32,1,0,1><<<dim3(32, 7, 1), 256, 0, stream>>>(h, 512, Bf1, 512,
            b1 + (size_t)n*2048, nullptr, ffn, 2048);
        // h += ffn @ W2 + b2  (K=2048 split 4)
        gemm16<512,16,0,1,0><<<dim3(8, 7, 4), 256, 0, stream>>>(ffn, 2048, Bf2, 2048,
            b2 + (size_t)n*512, h, nullptr, 512);
    }
    copyk<<<200, 256, 0, stream>>>(h, (float*)d_out, NLOC*512);
}